// Round 7
// baseline (111.468 us; speedup 1.0000x reference)
//
#include <hip/hip_runtime.h>
#include <math.h>

#define HW 512
#define NB 16
#define TX 16           // tile width
#define TY 16           // tile height
#define LDSW 24         // TX + 8 halo cols (float4-aligned)
#define LDSH 22         // TY + 6 halo rows
#define N_PIX (NB * HW * HW)     // 4194304
#define NBLK (32 * 32 * NB)      // 16384 phase-1 blocks (single-wave each)

using f32x4 = __attribute__((ext_vector_type(4))) float;

// Force a float into an SGPR (uniform across wave).
__device__ __forceinline__ float sgpr_f(float v) {
    return __uint_as_float(__builtin_amdgcn_readfirstlane(__float_as_uint(v)));
}

// Phase 1: 16x16 tile per SINGLE-WAVE block; thread = 1 row x 4 cols.
// Design from rounds 3/4/6 counters:
//  - LDS staging (reuse at LDS latency) beat global streaming (R6: 54us,
//    20% VALUBusy -- waves parked in vmcnt waits on L1/L2 loads).
//  - Single-wave blocks (no barrier lockstep) beat 4-wave blocks (R3: 22% occ).
//  - New: 16384 blocks -> 24 resident waves/CU at launch_bounds(64,6)
//    (VGPR cap 80 vs ~50 live: no R2-style spill squeeze), and the 1x4
//    patch uses all 7 window rows uniformly -> ~500-instr body (I$-friendly),
//    22 ds_read_b128/thread, <=2-way LDS bank aliasing (free).
// dif via identity: sum w*relu(v-c) = sum w*max(v,c) - c*sum(w)  (2 ops/tap).
__global__ __launch_bounds__(64, 6) void li_phase1(
    const float* __restrict__ x, const float* __restrict__ kw,
    float* __restrict__ out_ratio, float* __restrict__ out_avg,
    float* __restrict__ out_dif, float* __restrict__ partials)
{
    __shared__ float tile[LDSH * LDSW];   // 2112 B

    const int tid = threadIdx.x;          // 0..63 (one wave)
    const int bx = blockIdx.x, by = blockIdx.y, b = blockIdx.z;
    const int x0 = bx * TX, y0 = by * TY;
    const float* xb = x + (size_t)b * (HW * HW);

    // 49 weights pinned to SGPRs; W = sum of all weights (center weight is 0).
    float w[49];
    float W = 0.f;
#pragma unroll
    for (int i = 0; i < 49; i++) { w[i] = sgpr_f(kw[i]); W += w[i]; }

    // Stage 22 x 24 tile with zero halo: 132 float4s, 3 guarded loads/thread.
#pragma unroll
    for (int k = 0; k < 3; k++) {
        const int idx = tid + k * 64;
        if (idx < LDSH * (LDSW / 4)) {
            const int r  = idx / (LDSW / 4);
            const int c4 = idx - r * (LDSW / 4);
            const int gy = y0 - 3 + r;
            const int gx = x0 - 4 + c4 * 4;
            float4 v = make_float4(0.f, 0.f, 0.f, 0.f);
            if ((unsigned)gy < HW && (unsigned)gx <= (unsigned)(HW - 4))
                v = *(const float4*)(xb + gy * HW + gx);
            *(float4*)&tile[r * LDSW + c4 * 4] = v;
        }
    }
    __syncthreads();   // single wave: lgkmcnt drain + trivial barrier

    const int cx = tid & 3;          // column group: output cols 4cx..4cx+3
    const int cy = tid >> 2;         // output row within tile (0..15)
    const int colw = 4 * cx;         // LDS word col of v[0] (= tile col - 4)

    // Center: 1 aligned float4 (LDS row cy+3, own columns).
    float cen[4];
    {
        float4 c4v = *(const float4*)&tile[(cy + 3) * LDSW + colw + 4];
        cen[0] = c4v.x; cen[1] = c4v.y; cen[2] = c4v.z; cen[3] = c4v.w;
    }

    float dif[4]  = {0.f, 0.f, 0.f, 0.f};
    float bsum[4] = {0.f, 0.f, 0.f, 0.f};

    // 7 window rows, each used exactly once: 3 aligned b128 per row.
    // Row covers LDS words colw..colw+11 (we need colw+1..colw+10).
#pragma unroll
    for (int di = 0; di < 7; di++) {
        const float* base = &tile[(cy + di) * LDSW + colw];
        float4 q0 = *(const float4*)base;
        float4 q1 = *(const float4*)(base + 4);
        float4 q2 = *(const float4*)(base + 8);
        float v[12] = {q0.x, q0.y, q0.z, q0.w,
                       q1.x, q1.y, q1.z, q1.w,
                       q2.x, q2.y, q2.z, q2.w};

        // Sliding 7-wide row sums for the 4 output columns.
        float s0 = ((v[1] + v[2]) + (v[3] + v[4])) + ((v[5] + v[6]) + v[7]);
        float s1 = s0 + (v[8]  - v[1]);
        float s2 = s1 + (v[9]  - v[2]);
        float s3 = s2 + (v[10] - v[3]);
        bsum[0] += s0; bsum[1] += s1; bsum[2] += s2; bsum[3] += s3;

#pragma unroll
        for (int dj = 0; dj < 7; dj++) {
            if (di == 3 && dj == 3) continue;   // center weight == 0
            const float wv = w[di * 7 + dj];
#pragma unroll
            for (int j = 0; j < 4; j++)
                dif[j] = fmaf(wv, fmaxf(v[1 + j + dj], cen[j]), dif[j]);
        }
    }

    // Epilogue: one float4 store per array (plain, full-sector, L2-combined).
    const size_t gi = (size_t)b * (HW * HW) + (size_t)(y0 + cy) * HW + x0 + colw;
    float av[4], dv[4], rv[4];
    float ss = 0.f;
#pragma unroll
    for (int j = 0; j < 4; j++) {
        av[j] = __expf(-bsum[j] * (1.0f / 49.0f));
        dv[j] = fmaf(-W, cen[j], dif[j]);               // subtract c*sum(w)
        const float spv = 0.1f * av[j] + 0.9f * dv[j];  // > 0 always
        rv[j] = cen[j] * __builtin_amdgcn_rcpf(spv);
        ss = fmaf(spv, spv, ss);
    }
    *(f32x4*)(out_avg + gi)   = (f32x4){av[0], av[1], av[2], av[3]};
    *(f32x4*)(out_dif + gi)   = (f32x4){dv[0], dv[1], dv[2], dv[3]};
    *(f32x4*)(out_ratio + gi) = (f32x4){rv[0], rv[1], rv[2], rv[3]};

    // Wave reduction of ss -> partials[bid] (single wave: shuffles only).
#pragma unroll
    for (int off = 32; off > 0; off >>= 1)
        ss += __shfl_down(ss, off, 64);
    if (tid == 0)
        partials[bx + 32 * (by + 32 * b)] = ss;
}

// Phase 2 (reduce fused): each block sums the 16384 partials itself (64 KB,
// L2-resident), then masks its 4096-element slice: mask = (ratio > 1/sqrt(ss)).
__global__ __launch_bounds__(256) void li_phase2(
    const float* __restrict__ partials, float* __restrict__ io)
{
    __shared__ float wsum[4];
    __shared__ float s_inv;
    const int tid = threadIdx.x;

    float s = 0.f;
#pragma unroll
    for (int i = 0; i < NBLK / 256; i++)
        s += partials[tid + i * 256];
#pragma unroll
    for (int off = 32; off > 0; off >>= 1)
        s += __shfl_down(s, off, 64);
    if ((tid & 63) == 0) wsum[tid >> 6] = s;
    __syncthreads();
    if (tid == 0)
        s_inv = 1.0f / sqrtf((wsum[0] + wsum[1]) + (wsum[2] + wsum[3]));
    __syncthreads();

    const float inv = s_inv;
    const int base = blockIdx.x * 4096 + tid * 4;
#pragma unroll
    for (int k = 0; k < 4; k++) {
        const int i = base + k * 1024;
        float4 r = *(const float4*)(io + i);
        float4 m;
        m.x = (r.x > inv) ? 1.f : 0.f;
        m.y = (r.y > inv) ? 1.f : 0.f;
        m.z = (r.z > inv) ? 1.f : 0.f;
        m.w = (r.w > inv) ? 1.f : 0.f;
        *(float4*)(io + i) = m;
    }
}

extern "C" void kernel_launch(void* const* d_in, const int* in_sizes, int n_in,
                              void* d_out, int out_size, void* d_ws, size_t ws_size,
                              hipStream_t stream) {
    const float* x  = (const float*)d_in[0];
    const float* kw = (const float*)d_in[1];
    float* out   = (float*)d_out;
    float* ratio = out;                       // becomes mask after phase 2
    float* avg   = out + N_PIX;
    float* dif   = out + 2 * (size_t)N_PIX;
    float* ws    = (float*)d_ws;              // [0,NBLK): partials (fully written)

    dim3 g(HW / TX, HW / TY, NB);   // 32 x 32 x 16 = 16384 single-wave blocks
    li_phase1<<<g, 64, 0, stream>>>(x, kw, ratio, avg, dif, ws);
    li_phase2<<<N_PIX / 4096, 256, 0, stream>>>(ws, ratio);
}